// Round 12
// baseline (399.843 us; speedup 1.0000x reference)
//
#include <hip/hip_runtime.h>

// Pipeline (R24 = R23 + agg->matmul fusion through LDS; a0 and h2 never hit
// global):
//   h0 = bf16(dis*relu(relu([x|st]@W1+b1)@W2+b2))   [N,64]  k_mlp
//   P  = bf16(dis*(relu(agg64(h0)@Wg0+bg0)@Wg1))    [N,128] k_agg_cmm (agg0+cmm)
//   Q  = bf16(agg128(P,+bg1,relu,*dis)@Wg2)         [N,64]  k_agg_mm5 (agg1+mmx5)
//   out= dis[d]*(sum+self)+bg2                      [N,64]  agg2 -> d_out (fp32)
//
// Fusion invariant: block = 64 nodes, wave wv owns nodes wv*16..wv*16+15.
// MFMA A-fragments of wave wv read LDS rows wv*16+(lane&15) -- the SAME rows
// the wave itself agg'd -> no cross-wave deps, NO barrier between agg phase
// and MFMA phases (waves drain independently; no slowest-wave stall).
// Agg inner loops copied verbatim from R23 (same staircases, same order) ->
// absmax must stay bit-exact at 0.00390625.
// R21 lesson kept: bucketed CSR = write coalescing (random 4B global stores
// cost 16x via line write-allocate). R18 lesson: agg gathers are at the
// compulsory per-XCD traffic wall (~193MB), structure-independent.
// Math: out[d] = dis[d]*(sum_s dis[s]*P[s] + dis[d]*P[d]); with P'[i]=dis[i]*P[i]
// this is dis[d]*(sum_s P'[s] + P'[d]) -- per-edge weights vanish.
// MFMA layouts (guide-verified): A[m=lane&15][k=(lane>>4)*8+j], B mirrored,
// C/D[row=(lane>>4)*4+reg][col=lane&15].

__device__ __forceinline__ unsigned short bf16rne(float f) {
    unsigned u = __float_as_uint(f);
    unsigned r = (u + 0x7fffu + ((u >> 16) & 1u)) >> 16;
    return (unsigned short)r;
}
__device__ __forceinline__ float bf16lo(unsigned v) { return __uint_as_float(v << 16); }
__device__ __forceinline__ float bf16hi(unsigned v) { return __uint_as_float(v & 0xffff0000u); }

using bf16x8 = __attribute__((ext_vector_type(8))) short;
using f32x4  = __attribute__((ext_vector_type(4))) float;

__device__ __forceinline__ bf16x8 pack8(float4 u, float4 v) {
    bf16x8 r;
    r[0] = (short)bf16rne(u.x); r[1] = (short)bf16rne(u.y);
    r[2] = (short)bf16rne(u.z); r[3] = (short)bf16rne(u.w);
    r[4] = (short)bf16rne(v.x); r[5] = (short)bf16rne(v.y);
    r[6] = (short)bf16rne(v.z); r[7] = (short)bf16rne(v.w);
    return r;
}

// ---------------- graph preprocessing: bucketed CSR (dst>>8 buckets) --------
// ep entry: src | ((dst & 255) << 20)   (requires n <= 2^20)

__global__ __launch_bounds__(256) void k_hist(const int* __restrict__ dst, int e, int nb,
                                              int* __restrict__ gh, int* __restrict__ bh) {
    __shared__ int h[512];
    const int t = threadIdx.x;
    h[t] = 0; h[t + 256] = 0;
    __syncthreads();
    const int base = blockIdx.x * 4096;
    const int end = min(base + 4096, e);
    for (int i = base + t; i < end; i += 256) atomicAdd(&h[dst[i] >> 8], 1);
    __syncthreads();
    int* bhrow = bh + (size_t)blockIdx.x * 512;
    for (int b = t; b < nb; b += 256) {
        int c = h[b];
        bhrow[b] = c;
        if (c) atomicAdd(&gh[b], c);
    }
}

__global__ __launch_bounds__(512) void k_scan(const int* __restrict__ gh, int nb, int e, int n,
                                              int* __restrict__ bbase, int* __restrict__ gcur,
                                              int* __restrict__ offs) {
    __shared__ int sm[512];
    const int t = threadIdx.x;
    int v = (t < nb) ? gh[t] : 0;
    sm[t] = v;
    __syncthreads();
    for (int off = 1; off < 512; off <<= 1) {
        int add = (t >= off) ? sm[t - off] : 0;
        __syncthreads();
        sm[t] += add;
        __syncthreads();
    }
    if (t < nb) {
        int excl = sm[t] - v;
        bbase[t] = excl;
        gcur[t] = excl;
    }
    if (t == 0) { bbase[nb] = e; offs[n] = e; }
}

__global__ __launch_bounds__(256) void k_scatter1(const int* __restrict__ src,
                                                  const int* __restrict__ dst, int e, int nb,
                                                  int* __restrict__ gcur,
                                                  const int* __restrict__ bh,
                                                  int* __restrict__ ep) {
    __shared__ int h[512];
    __shared__ int cbase[512];
    const int t = threadIdx.x;
    h[t] = 0; h[t + 256] = 0;
    __syncthreads();
    const int* bhrow = bh + (size_t)blockIdx.x * 512;
    for (int b = t; b < nb; b += 256) {
        int c = bhrow[b];
        cbase[b] = c ? atomicAdd(&gcur[b], c) : 0;
    }
    __syncthreads();
    const int base = blockIdx.x * 4096;
    const int end = min(base + 4096, e);
    for (int i = base + t; i < end; i += 256) {
        int d = dst[i];
        int bn = d >> 8;
        int r = atomicAdd(&h[bn], 1);
        ep[cbase[bn] + r] = src[i] | ((d & 255) << 20);
    }
}

__global__ __launch_bounds__(256) void k_build(const int* __restrict__ ep,
                                               const int* __restrict__ bbase, int n,
                                               int* __restrict__ offs,
                                               int* __restrict__ ssrc,
                                               float* __restrict__ dis) {
    __shared__ int cnt[256];
    __shared__ int sm[256];
    __shared__ int cur[256];
    const int t = threadIdx.x;
    const int b = blockIdx.x;
    const int lo = bbase[b];
    const int hi = bbase[b + 1];
    cnt[t] = 0;
    __syncthreads();
    for (int i = lo + t; i < hi; i += 256) atomicAdd(&cnt[(ep[i] >> 20) & 255], 1);
    __syncthreads();
    int v = cnt[t];
    sm[t] = v;
    __syncthreads();
    for (int off = 1; off < 256; off <<= 1) {
        int add = (t >= off) ? sm[t - off] : 0;
        __syncthreads();
        sm[t] += add;
        __syncthreads();
    }
    const int excl = sm[t] - v;
    const int node = (b << 8) + t;
    if (node < n) {
        offs[node] = lo + excl;
        dis[node] = rsqrtf(1.0f + (float)v);
    }
    cur[t] = lo + excl;
    __syncthreads();
    for (int i = lo + t; i < hi; i += 256) {
        int p = ep[i];
        int pos = atomicAdd(&cur[(p >> 20) & 255], 1);
        ssrc[pos] = p & 0xFFFFF;
    }
}

// ---------------- W -> MFMA fragment-ordered bf16 (fused x5) ----------------
// Wf[((kt*CT+ct)*64+lane)*8 + j] = bf16(W[kt*32+(lane>>4)*8+j][ct*16+(lane&15)])
// Segments: [0,12288) W1 96x128 -> Fa; [12288,20480) W2 128x64 -> Fb;
// [20480,28672) Wg0 64x128 -> F0; [28672,45056) Wg1 128x128 -> F1;
// [45056,53248) Wg2 128x64 -> F2.  Grid: 208 blocks x 256.

__global__ void k_wprep5(const float* __restrict__ W1, const float* __restrict__ W2,
                         const float* __restrict__ G0, const float* __restrict__ G1,
                         const float* __restrict__ G2,
                         unsigned short* __restrict__ Fa, unsigned short* __restrict__ Fb,
                         unsigned short* __restrict__ F0, unsigned short* __restrict__ F1,
                         unsigned short* __restrict__ F2) {
    int t = blockIdx.x * 256 + threadIdx.x;
    const float* W;
    unsigned short* Wf;
    int FOUT;
    if (t < 12288) { W = W1; Wf = Fa; FOUT = 128; }
    else if (t < 20480) { t -= 12288; W = W2; Wf = Fb; FOUT = 64; }
    else if (t < 28672) { t -= 20480; W = G0; Wf = F0; FOUT = 128; }
    else if (t < 45056) { t -= 28672; W = G1; Wf = F1; FOUT = 128; }
    else { t -= 45056; W = G2; Wf = F2; FOUT = 64; }
    const int CT = FOUT / 16;
    int j = t & 7;
    int lane = (t >> 3) & 63;
    int ct = (t >> 9) % CT;
    int kt = t / (512 * CT);
    int k = kt * 32 + (lane >> 4) * 8 + j;
    int c = ct * 16 + (lane & 15);
    Wf[t] = bf16rne(W[(size_t)k * FOUT + c]);
}

// ---------------- fused MLP: h0 = bf16(dis*relu(relu([x|st]@W1+b1)@W2+b2)) --

__global__ __launch_bounds__(256) void k_mlp(const float* __restrict__ x,
                                             const float* __restrict__ st,
                                             const unsigned short* __restrict__ Wa,
                                             const float* __restrict__ b1,
                                             const unsigned short* __restrict__ Wb,
                                             const float* __restrict__ b2,
                                             const float* __restrict__ dis,
                                             unsigned short* __restrict__ h0, int n) {
    constexpr int ROWB = 136;
    __shared__ unsigned short As[64 * ROWB];

    const int t = threadIdx.x;
    const int wv = t >> 6;
    const int lane = t & 63;
    const int rowBase = blockIdx.x * 64 + wv * 16;
    const int m = lane & 15;
    const int q = lane >> 4;

    // ---- phase 1: A = relu([x|st]@W1+b1), K=96, CT=8 ----
    {
        f32x4 acc[8];
#pragma unroll
        for (int c = 0; c < 8; c++) acc[c] = (f32x4){0.f, 0.f, 0.f, 0.f};

        int arow = rowBase + m;
        if (arow >= n) arow = n - 1;
        const float* xp = x + (size_t)arow * 64 + q * 8;
        const float* sp = st + (size_t)arow * 32 + q * 8;

        bf16x8 a0 = pack8(*(const float4*)(xp), *(const float4*)(xp + 4));
        bf16x8 a1 = pack8(*(const float4*)(xp + 32), *(const float4*)(xp + 36));
        bf16x8 a2 = pack8(*(const float4*)(sp), *(const float4*)(sp + 4));

        const bf16x8* wfp = (const bf16x8*)Wa;
#pragma unroll
        for (int c = 0; c < 8; c++) {
            acc[c] = __builtin_amdgcn_mfma_f32_16x16x32_bf16(a0, wfp[c * 64 + lane], acc[c], 0, 0, 0);
            acc[c] = __builtin_amdgcn_mfma_f32_16x16x32_bf16(a1, wfp[(8 + c) * 64 + lane], acc[c], 0, 0, 0);
            acc[c] = __builtin_amdgcn_mfma_f32_16x16x32_bf16(a2, wfp[(16 + c) * 64 + lane], acc[c], 0, 0, 0);
        }

        float bv[8];
#pragma unroll
        for (int c = 0; c < 8; c++) bv[c] = b1[c * 16 + m];

        const int lrow = wv * 16 + q * 4;
#pragma unroll
        for (int r = 0; r < 4; r++) {
#pragma unroll
            for (int c = 0; c < 8; c++) {
                float v = fmaxf(acc[c][r] + bv[c], 0.f);
                As[(lrow + r) * ROWB + c * 16 + m] = bf16rne(v);
            }
        }
    }
    // wave-local rows: phase 2 reads only rows wv*16+m (own wave) -- no barrier

    // ---- phase 2: h0 = dis*relu(A@W2+b2), K=128, CT=4 ----
    {
        f32x4 acc[4];
#pragma unroll
        for (int c = 0; c < 4; c++) acc[c] = (f32x4){0.f, 0.f, 0.f, 0.f};

        const unsigned short* ap = As + (wv * 16 + m) * ROWB + q * 8;
        const bf16x8* wfp = (const bf16x8*)Wb;
#pragma unroll
        for (int kt = 0; kt < 4; kt++) {
            bf16x8 a = *(const bf16x8*)(ap + kt * 32);
#pragma unroll
            for (int c = 0; c < 4; c++) {
                acc[c] = __builtin_amdgcn_mfma_f32_16x16x32_bf16(a, wfp[(kt * 4 + c) * 64 + lane], acc[c], 0, 0, 0);
            }
        }

        float bv[4];
#pragma unroll
        for (int c = 0; c < 4; c++) bv[c] = b2[c * 16 + m];

        const int crow = rowBase + q * 4;
#pragma unroll
        for (int r = 0; r < 4; r++) {
            int rr = crow + r;
            if (rr >= n) continue;
            const float sc = dis[rr];
#pragma unroll
            for (int c = 0; c < 4; c++) {
                float v = fmaxf(acc[c][r] + bv[c], 0.f) * sc;
                h0[(size_t)rr * 64 + c * 16 + m] = bf16rne(v);
            }
        }
    }
}

// ---------------- fused agg0 + conv mm: P = dis*(relu(agg64(h0)@Wg0+bg0)@Wg1)
// Block = 64 nodes; wave wv aggs nodes wv*16..+15 (F=64, half-wave split,
// staircase 32/8/2/1 -- verbatim R23 order) into LDS a0-tile [64][72] bf16,
// then runs cmm phases 1+2 on its OWN rows. No barriers (wave-local).

__global__ __launch_bounds__(256) void k_agg_cmm(const unsigned short* __restrict__ h0,
                                                 const int* __restrict__ offs,
                                                 const int* __restrict__ ssrc,
                                                 const float* __restrict__ dis,
                                                 const unsigned short* __restrict__ W0,
                                                 const float* __restrict__ bg0,
                                                 const unsigned short* __restrict__ W1,
                                                 unsigned short* __restrict__ P, int n) {
    constexpr int RA = 72;   // a0 tile row stride (bf16): 144B -> 2-way b128, free
    constexpr int RB = 136;  // h1 tile row stride
    __shared__ unsigned short As[64 * RA];
    __shared__ unsigned short Hs[64 * RB];

    const int t = threadIdx.x;
    const int wv = t >> 6;
    const int lane = t & 63;
    const int half = lane >> 5;
    const int hl = lane & 31;
    const unsigned* hw32 = (const unsigned*)h0;
    unsigned* As32 = (unsigned*)As;

#define ADD2(r) do { accL += bf16lo(r); accH += bf16hi(r); } while (0)
    for (int i = 0; i < 16; i++) {
        const int lrow = wv * 16 + i;
        const int node = blockIdx.x * 64 + lrow;
        if (node >= n) {
            if (half == 0) As32[lrow * 36 + hl] = 0;
            continue;
        }
        const int jb = __builtin_amdgcn_readfirstlane(offs[node]);
        const int je = __builtin_amdgcn_readfirstlane(offs[node + 1]);
        float accL = 0.f, accH = 0.f;
        int j = jb;
        for (; j + 32 <= je; j += 32) {
            int t00 = ssrc[j + 0],  t01 = ssrc[j + 1],  t02 = ssrc[j + 2],  t03 = ssrc[j + 3];
            int t04 = ssrc[j + 4],  t05 = ssrc[j + 5],  t06 = ssrc[j + 6],  t07 = ssrc[j + 7];
            int t08 = ssrc[j + 8],  t09 = ssrc[j + 9],  t10 = ssrc[j + 10], t11 = ssrc[j + 11];
            int t12 = ssrc[j + 12], t13 = ssrc[j + 13], t14 = ssrc[j + 14], t15 = ssrc[j + 15];
            int t16 = ssrc[j + 16], t17 = ssrc[j + 17], t18 = ssrc[j + 18], t19 = ssrc[j + 19];
            int t20 = ssrc[j + 20], t21 = ssrc[j + 21], t22 = ssrc[j + 22], t23 = ssrc[j + 23];
            int t24 = ssrc[j + 24], t25 = ssrc[j + 25], t26 = ssrc[j + 26], t27 = ssrc[j + 27];
            int t28 = ssrc[j + 28], t29 = ssrc[j + 29], t30 = ssrc[j + 30], t31 = ssrc[j + 31];
            int e0 = half ? t01 : t00;
            int e1 = half ? t03 : t02;
            int e2 = half ? t05 : t04;
            int e3 = half ? t07 : t06;
            int e4 = half ? t09 : t08;
            int e5 = half ? t11 : t10;
            int e6 = half ? t13 : t12;
            int e7 = half ? t15 : t14;
            int e8 = half ? t17 : t16;
            int e9 = half ? t19 : t18;
            int ea = half ? t21 : t20;
            int eb = half ? t23 : t22;
            int ec = half ? t25 : t24;
            int ed = half ? t27 : t26;
            int ee = half ? t29 : t28;
            int ef = half ? t31 : t30;
            unsigned r0 = hw32[(size_t)e0 * 32 + hl];
            unsigned r1 = hw32[(size_t)e1 * 32 + hl];
            unsigned r2 = hw32[(size_t)e2 * 32 + hl];
            unsigned r3 = hw32[(size_t)e3 * 32 + hl];
            unsigned r4 = hw32[(size_t)e4 * 32 + hl];
            unsigned r5 = hw32[(size_t)e5 * 32 + hl];
            unsigned r6 = hw32[(size_t)e6 * 32 + hl];
            unsigned r7 = hw32[(size_t)e7 * 32 + hl];
            unsigned r8 = hw32[(size_t)e8 * 32 + hl];
            unsigned r9 = hw32[(size_t)e9 * 32 + hl];
            unsigned ra = hw32[(size_t)ea * 32 + hl];
            unsigned rb = hw32[(size_t)eb * 32 + hl];
            unsigned rc = hw32[(size_t)ec * 32 + hl];
            unsigned rd = hw32[(size_t)ed * 32 + hl];
            unsigned re = hw32[(size_t)ee * 32 + hl];
            unsigned rf = hw32[(size_t)ef * 32 + hl];
            ADD2(r0); ADD2(r1); ADD2(r2); ADD2(r3);
            ADD2(r4); ADD2(r5); ADD2(r6); ADD2(r7);
            ADD2(r8); ADD2(r9); ADD2(ra); ADD2(rb);
            ADD2(rc); ADD2(rd); ADD2(re); ADD2(rf);
        }
        for (; j + 8 <= je; j += 8) {
            int t0 = ssrc[j + 0], t1 = ssrc[j + 1], t2 = ssrc[j + 2], t3 = ssrc[j + 3];
            int t4 = ssrc[j + 4], t5 = ssrc[j + 5], t6 = ssrc[j + 6], t7 = ssrc[j + 7];
            int e0 = half ? t1 : t0;
            int e1 = half ? t3 : t2;
            int e2 = half ? t5 : t4;
            int e3 = half ? t7 : t6;
            unsigned r0 = hw32[(size_t)e0 * 32 + hl];
            unsigned r1 = hw32[(size_t)e1 * 32 + hl];
            unsigned r2 = hw32[(size_t)e2 * 32 + hl];
            unsigned r3 = hw32[(size_t)e3 * 32 + hl];
            ADD2(r0); ADD2(r1); ADD2(r2); ADD2(r3);
        }
        for (; j + 2 <= je; j += 2) {
            int t0 = ssrc[j], t1 = ssrc[j + 1];
            int e0 = half ? t1 : t0;
            unsigned r = hw32[(size_t)e0 * 32 + hl];
            ADD2(r);
        }
        if (j < je) {
            int s = ssrc[j];
            unsigned r = hw32[(size_t)s * 32 + hl];
            if (half == 0) { ADD2(r); }
        }
        accL += __shfl_xor(accL, 32);
        accH += __shfl_xor(accH, 32);
        if (half == 0) {
            unsigned sv = hw32[(size_t)node * 32 + hl];
            const float di = dis[node];
            float v0 = (accL + bf16lo(sv)) * di;
            float v1 = (accH + bf16hi(sv)) * di;
            As32[lrow * 36 + hl] = (unsigned)bf16rne(v0) | ((unsigned)bf16rne(v1) << 16);
        }
    }
#undef ADD2

    const int m = lane & 15;
    const int q = lane >> 4;

    // ---- cmm phase 1: h1 = relu(a0@Wg0+bg0), K=64, CT=8 (A from As) ----
    {
        f32x4 acc[8];
#pragma unroll
        for (int c = 0; c < 8; c++) acc[c] = (f32x4){0.f, 0.f, 0.f, 0.f};

        const unsigned short* ap = As + (wv * 16 + m) * RA + q * 8;
        const bf16x8* wfp = (const bf16x8*)W0;
#pragma unroll
        for (int kt = 0; kt < 2; kt++) {
            bf16x8 a = *(const bf16x8*)(ap + kt * 32);
#pragma unroll
            for (int c = 0; c < 8; c++) {
                acc[c] = __builtin_amdgcn_mfma_f32_16x16x32_bf16(a, wfp[(kt * 8 + c) * 64 + lane], acc[c], 0, 0, 0);
            }
        }

        float bv[8];
#pragma unroll
        for (int c = 0; c < 8; c++) bv[c] = bg0[c * 16 + m];

        const int lrow = wv * 16 + q * 4;
#pragma unroll
        for (int r = 0; r < 4; r++) {
#pragma unroll
            for (int c = 0; c < 8; c++) {
                float v = fmaxf(acc[c][r] + bv[c], 0.f);
                Hs[(lrow + r) * RB + c * 16 + m] = bf16rne(v);
            }
        }
    }

    // ---- cmm phase 2: P = dis*(h1@Wg1), K=128, CT=8 (A from Hs) ----
    {
        f32x4 acc[8];
#pragma unroll
        for (int c = 0; c < 8; c++) acc[c] = (f32x4){0.f, 0.f, 0.f, 0.f};

        const unsigned short* ap = Hs + (wv * 16 + m) * RB + q * 8;
        const bf16x8* wfp = (const bf16x8*)W1;
#pragma unroll
        for (int kt = 0; kt < 4; kt++) {
            bf16x8 a = *(const bf16x8*)(ap + kt * 32);
#pragma unroll
            for (int c = 0; c < 8; c++) {
                acc[c] = __builtin_amdgcn_mfma_f32_16x16x32_bf16(a, wfp[(kt * 8 + c) * 64 + lane], acc[c], 0, 0, 0);
            }
        }

        const int crow = blockIdx.x * 64 + wv * 16 + q * 4;
#pragma unroll
        for (int r = 0; r < 4; r++) {
            int rr = crow + r;
            if (rr >= n) continue;
            const float sc = dis[rr];
#pragma unroll
            for (int c = 0; c < 8; c++) {
                P[(size_t)rr * 128 + c * 16 + m] = bf16rne(acc[c][r] * sc);
            }
        }
    }
}

// ---------------- fused agg1 + mmx5: Q = agg128(P,+bg1,relu,*dis)@Wg2 -------
// Wave aggs its 16 nodes (F=128, lane owns dword, staircase 16/4/1 -- verbatim
// R23) into LDS h2'-tile [64][136] bf16, then K=128/FOUT=64 MFMA on own rows.

__global__ __launch_bounds__(256) void k_agg_mm5(const unsigned short* __restrict__ Pin,
                                                 const float* __restrict__ bg1,
                                                 const int* __restrict__ offs,
                                                 const int* __restrict__ ssrc,
                                                 const float* __restrict__ dis,
                                                 const unsigned short* __restrict__ W2f,
                                                 unsigned short* __restrict__ Q, int n) {
    constexpr int RB = 136;
    __shared__ unsigned short As[64 * RB];
    unsigned* As32 = (unsigned*)As;  // row stride 68 dwords

    const int t = threadIdx.x;
    const int wv = t >> 6;
    const int lane = t & 63;
    const unsigned* hw32 = (const unsigned*)Pin;
    const float2 bb = *(const float2*)(bg1 + lane * 2);

#define ADD2(r) do { accL += bf16lo(r); accH += bf16hi(r); } while (0)
    for (int i = 0; i < 16; i++) {
        const int lrow = wv * 16 + i;
        const int node = blockIdx.x * 64 + lrow;
        if (node >= n) {
            As32[lrow * 68 + lane] = 0;
            continue;
        }
        const int jb = __builtin_amdgcn_readfirstlane(offs[node]);
        const int je = __builtin_amdgcn_readfirstlane(offs[node + 1]);
        float accL = 0.f, accH = 0.f;
        int j = jb;
        for (; j + 16 <= je; j += 16) {
            int s0 = ssrc[j + 0], s1 = ssrc[j + 1], s2 = ssrc[j + 2], s3 = ssrc[j + 3];
            int s4 = ssrc[j + 4], s5 = ssrc[j + 5], s6 = ssrc[j + 6], s7 = ssrc[j + 7];
            int s8 = ssrc[j + 8], s9 = ssrc[j + 9], sa = ssrc[j + 10], sb = ssrc[j + 11];
            int sc = ssrc[j + 12], sd = ssrc[j + 13], se = ssrc[j + 14], sf = ssrc[j + 15];
            unsigned r0 = hw32[(size_t)s0 * 64 + lane];
            unsigned r1 = hw32[(size_t)s1 * 64 + lane];
            unsigned r2 = hw32[(size_t)s2 * 64 + lane];
            unsigned r3 = hw32[(size_t)s3 * 64 + lane];
            unsigned r4 = hw32[(size_t)s4 * 64 + lane];
            unsigned r5 = hw32[(size_t)s5 * 64 + lane];
            unsigned r6 = hw32[(size_t)s6 * 64 + lane];
            unsigned r7 = hw32[(size_t)s7 * 64 + lane];
            unsigned r8 = hw32[(size_t)s8 * 64 + lane];
            unsigned r9 = hw32[(size_t)s9 * 64 + lane];
            unsigned ra = hw32[(size_t)sa * 64 + lane];
            unsigned rb = hw32[(size_t)sb * 64 + lane];
            unsigned rc = hw32[(size_t)sc * 64 + lane];
            unsigned rd = hw32[(size_t)sd * 64 + lane];
            unsigned re = hw32[(size_t)se * 64 + lane];
            unsigned rf = hw32[(size_t)sf * 64 + lane];
            ADD2(r0); ADD2(r1); ADD2(r2); ADD2(r3);
            ADD2(r4); ADD2(r5); ADD2(r6); ADD2(r7);
            ADD2(r8); ADD2(r9); ADD2(ra); ADD2(rb);
            ADD2(rc); ADD2(rd); ADD2(re); ADD2(rf);
        }
        for (; j + 4 <= je; j += 4) {
            int s0 = ssrc[j + 0], s1 = ssrc[j + 1], s2 = ssrc[j + 2], s3 = ssrc[j + 3];
            unsigned r0 = hw32[(size_t)s0 * 64 + lane];
            unsigned r1 = hw32[(size_t)s1 * 64 + lane];
            unsigned r2 = hw32[(size_t)s2 * 64 + lane];
            unsigned r3 = hw32[(size_t)s3 * 64 + lane];
            ADD2(r0); ADD2(r1); ADD2(r2); ADD2(r3);
        }
        for (; j < je; j++) {
            int s = ssrc[j];
            unsigned r = hw32[(size_t)s * 64 + lane];
            ADD2(r);
        }
        unsigned sv = hw32[(size_t)node * 64 + lane];
        const float di = dis[node];
        float v0 = (accL + bf16lo(sv)) * di + bb.x;
        float v1 = (accH + bf16hi(sv)) * di + bb.y;
        v0 = fmaxf(v0, 0.f) * di;
        v1 = fmaxf(v1, 0.f) * di;
        As32[lrow * 68 + lane] = (unsigned)bf16rne(v0) | ((unsigned)bf16rne(v1) << 16);
    }
#undef ADD2

    // ---- mm phase: Q = h2'@Wg2, K=128, FOUT=64, CT=4 (A from As, own rows) --
    const int m = lane & 15;
    const int q = lane >> 4;
    f32x4 acc[4];
#pragma unroll
    for (int c = 0; c < 4; c++) acc[c] = (f32x4){0.f, 0.f, 0.f, 0.f};

    const unsigned short* ap = As + (wv * 16 + m) * RB + q * 8;
    const bf16x8* wfp = (const bf16x8*)W2f;
#pragma unroll
    for (int kt = 0; kt < 4; kt++) {
        bf16x8 a = *(const bf16x8*)(ap + kt * 32);
#pragma unroll
        for (int c = 0; c < 4; c++) {
            acc[c] = __builtin_amdgcn_mfma_f32_16x16x32_bf16(a, wfp[(kt * 4 + c) * 64 + lane], acc[c], 0, 0, 0);
        }
    }

    const int crow = blockIdx.x * 64 + wv * 16 + q * 4;
#pragma unroll
    for (int r = 0; r < 4; r++) {
        int rr = crow + r;
        if (rr >= n) continue;
#pragma unroll
        for (int c = 0; c < 4; c++) {
            Q[(size_t)rr * 64 + c * 16 + m] = bf16rne(acc[c][r]);
        }
    }
}

// ---------------- GCN aggregation (final, F=64, fp32 out) -------------------
// Same structure as R23's F=64 path. One wave per node; half-waves alternate
// edges; 32-edge chunks, staircase 32/8/2/1; shfl_xor(32) merge.

__global__ __launch_bounds__(256) void k_agg_fin(const unsigned short* __restrict__ hW,
                                                 const float* __restrict__ bias,
                                                 const float* __restrict__ dis,
                                                 const int* __restrict__ offs,
                                                 const int* __restrict__ ssrc,
                                                 float* __restrict__ outv, int n) {
    const int wv = threadIdx.x >> 6;
    const int lane = threadIdx.x & 63;
    const int node = blockIdx.x * 4 + wv;
    if (node >= n) return;
    const int jb = __builtin_amdgcn_readfirstlane(offs[node]);
    const int je = __builtin_amdgcn_readfirstlane(offs[node + 1]);
    const unsigned* hw32 = (const unsigned*)hW;
    const int half = lane >> 5;
    const int hl = lane & 31;

    float accL = 0.f, accH = 0.f;
#define ADD2(r) do { accL += bf16lo(r); accH += bf16hi(r); } while (0)
    int j = jb;
    for (; j + 32 <= je; j += 32) {
        int t00 = ssrc[j + 0],  t01 = ssrc[j + 1],  t02 = ssrc[j + 2],  t03 = ssrc[j + 3];
        int t04 = ssrc[j + 4],  t05 = ssrc[j + 5],  t06 = ssrc[j + 6],  t07 = ssrc[j + 7];
        int t08 = ssrc[j + 8],  t09 = ssrc[j + 9],  t10 = ssrc[j + 10], t11 = ssrc[j + 11];
        int t12 = ssrc[j + 12], t13 = ssrc[j + 13], t14 = ssrc[j + 14], t15 = ssrc[j + 15];
        int t16 = ssrc[j + 16], t17 = ssrc[j + 17], t18 = ssrc[j + 18], t19 = ssrc[j + 19];
        int t20 = ssrc[j + 20], t21 = ssrc[j + 21], t22 = ssrc[j + 22], t23 = ssrc[j + 23];
        int t24 = ssrc[j + 24], t25 = ssrc[j + 25], t26 = ssrc[j + 26], t27 = ssrc[j + 27];
        int t28 = ssrc[j + 28], t29 = ssrc[j + 29], t30 = ssrc[j + 30], t31 = ssrc[j + 31];
        int e0 = half ? t01 : t00;
        int e1 = half ? t03 : t02;
        int e2 = half ? t05 : t04;
        int e3 = half ? t07 : t06;
        int e4 = half ? t09 : t08;
        int e5 = half ? t11 : t10;
        int e6 = half ? t13 : t12;
        int e7 = half ? t15 : t14;
        int e8 = half ? t17 : t16;
        int e9 = half ? t19 : t18;
        int ea = half ? t21 : t20;
        int eb = half ? t23 : t22;
        int ec = half ? t25 : t24;
        int ed = half ? t27 : t26;
        int ee = half ? t29 : t28;
        int ef = half ? t31 : t30;
        unsigned r0 = hw32[(size_t)e0 * 32 + hl];
        unsigned r1 = hw32[(size_t)e1 * 32 + hl];
        unsigned r2 = hw32[(size_t)e2 * 32 + hl];
        unsigned r3 = hw32[(size_t)e3 * 32 + hl];
        unsigned r4 = hw32[(size_t)e4 * 32 + hl];
        unsigned r5 = hw32[(size_t)e5 * 32 + hl];
        unsigned r6 = hw32[(size_t)e6 * 32 + hl];
        unsigned r7 = hw32[(size_t)e7 * 32 + hl];
        unsigned r8 = hw32[(size_t)e8 * 32 + hl];
        unsigned r9 = hw32[(size_t)e9 * 32 + hl];
        unsigned ra = hw32[(size_t)ea * 32 + hl];
        unsigned rb = hw32[(size_t)eb * 32 + hl];
        unsigned rc = hw32[(size_t)ec * 32 + hl];
        unsigned rd = hw32[(size_t)ed * 32 + hl];
        unsigned re = hw32[(size_t)ee * 32 + hl];
        unsigned rf = hw32[(size_t)ef * 32 + hl];
        ADD2(r0); ADD2(r1); ADD2(r2); ADD2(r3);
        ADD2(r4); ADD2(r5); ADD2(r6); ADD2(r7);
        ADD2(r8); ADD2(r9); ADD2(ra); ADD2(rb);
        ADD2(rc); ADD2(rd); ADD2(re); ADD2(rf);
    }
    for (; j + 8 <= je; j += 8) {
        int t0 = ssrc[j + 0], t1 = ssrc[j + 1], t2 = ssrc[j + 2], t3 = ssrc[j + 3];
        int t4 = ssrc[j + 4], t5 = ssrc[j + 5], t6 = ssrc[j + 6], t7 = ssrc[j + 7];
        int e0 = half ? t1 : t0;
        int e1 = half ? t3 : t2;
        int e2 = half ? t5 : t4;
        int e3 = half ? t7 : t6;
        unsigned r0 = hw32[(size_t)e0 * 32 + hl];
        unsigned r1 = hw32[(size_t)e1 * 32 + hl];
        unsigned r2 = hw32[(size_t)e2 * 32 + hl];
        unsigned r3 = hw32[(size_t)e3 * 32 + hl];
        ADD2(r0); ADD2(r1); ADD2(r2); ADD2(r3);
    }
    for (; j + 2 <= je; j += 2) {
        int t0 = ssrc[j], t1 = ssrc[j + 1];
        int e0 = half ? t1 : t0;
        unsigned r = hw32[(size_t)e0 * 32 + hl];
        ADD2(r);
    }
    if (j < je) {
        int s = ssrc[j];
        unsigned r = hw32[(size_t)s * 32 + hl];
        if (half == 0) { ADD2(r); }
    }
#undef ADD2
    accL += __shfl_xor(accL, 32);
    accH += __shfl_xor(accH, 32);
    if (half == 0) {
        unsigned sv = hw32[(size_t)node * 32 + hl];
        const float di = dis[node];
        float2 bb = *(const float2*)(bias + hl * 2);
        float v0 = (accL + bf16lo(sv)) * di + bb.x;
        float v1 = (accH + bf16hi(sv)) * di + bb.y;
        *(float2*)(outv + (size_t)node * 64 + hl * 2) = make_float2(v0, v1);
    }
}

// ---------------- launch -----------------------------------------------------

extern "C" void kernel_launch(void* const* d_in, const int* in_sizes, int n_in,
                              void* d_out, int out_size, void* d_ws, size_t ws_size,
                              hipStream_t stream) {
    const float* x   = (const float*)d_in[0];
    const float* st  = (const float*)d_in[1];
    const int*   src = (const int*)d_in[2];
    const int*   dst = (const int*)d_in[3];
    const float* W1  = (const float*)d_in[4];
    const float* b1  = (const float*)d_in[5];
    const float* W2  = (const float*)d_in[6];
    const float* b2  = (const float*)d_in[7];
    const float* Wg0 = (const float*)d_in[8];
    const float* bg0 = (const float*)d_in[9];
    const float* Wg1 = (const float*)d_in[10];
    const float* bg1 = (const float*)d_in[11];
    const float* Wg2 = (const float*)d_in[12];
    const float* bg2 = (const float*)d_in[13];

    const int n = in_sizes[0] / 64;  // IN_DIM = 64
    const int e = in_sizes[2];
    const int nb = (n + 255) >> 8;
    const int gE4k = (e + 4095) / 4096;

    char* wp = (char*)d_ws;
    auto carve = [&](size_t bytes) {
        void* p = (void*)wp;
        wp += (bytes + 255) & ~(size_t)255;
        return p;
    };
    int*   ghist = (int*)carve(512 * 4);
    int*   gcur  = (int*)carve(512 * 4);
    int*   bbase = (int*)carve(513 * 4);
    int*   bh    = (int*)carve((size_t)gE4k * 512 * 4);
    int*   offs  = (int*)carve((size_t)(n + 1) * 4);
    float* dis   = (float*)carve((size_t)n * 4);
    int*   ssrc  = (int*)carve((size_t)e * 4);
    char*  R3    = (char*)carve((size_t)n * 128 * 4);  // ep (dead after build)
    char*  R2    = (char*)carve((size_t)n * 64 * 2);   // h0 -> Q
    unsigned short* Waf = (unsigned short*)carve((size_t)96 * 128 * 2);
    unsigned short* Wbf = (unsigned short*)carve((size_t)128 * 64 * 2);
    unsigned short* W0f = (unsigned short*)carve((size_t)64 * 128 * 2);
    unsigned short* W1f = (unsigned short*)carve((size_t)128 * 128 * 2);
    unsigned short* W2f = (unsigned short*)carve((size_t)128 * 64 * 2);

    // aliases (stream-ordered lifetimes):
    int* ep = (int*)R3;                                   // dead after k_build
    unsigned short* h0 = (unsigned short*)R2;             // k_mlp out (dis-scaled)
    unsigned short* Q  = (unsigned short*)R2;             // k_agg_mm5 out (h0 dead)
    unsigned short* P  = (unsigned short*)d_out;          // k_agg_cmm out (n*128 bf16)

    hipMemsetAsync(ghist, 0, 512 * 4, stream);

    const int gN64 = (n + 63) / 64;
    const int gAgg = (n + 3) / 4;

    // graph prep (bucketed CSR: write-coalesced scatter)
    k_hist<<<gE4k, 256, 0, stream>>>(dst, e, nb, ghist, bh);
    k_scan<<<1, 512, 0, stream>>>(ghist, nb, e, n, bbase, gcur, offs);
    k_scatter1<<<gE4k, 256, 0, stream>>>(src, dst, e, nb, gcur, bh, ep);
    k_build<<<nb, 256, 0, stream>>>(ep, bbase, n, offs, ssrc, dis);

    // W fragment prep (fused x5): 53248 elements = 208 blocks
    k_wprep5<<<208, 256, 0, stream>>>(W1, W2, Wg0, Wg1, Wg2, Waf, Wbf, W0f, W1f, W2f);

    // fused MLP: h0 = dis*relu(relu([x|st]@W1+b1)@W2+b2)
    k_mlp<<<gN64, 256, 0, stream>>>(x, st, Waf, b1, Wbf, b2, dis, h0, n);

    // conv0+conv1-mm fused: P = dis*(relu(agg64(h0)@Wg0+bg0)@Wg1)
    k_agg_cmm<<<gN64, 256, 0, stream>>>(h0, offs, ssrc, dis, W0f, bg0, W1f, P, n);

    // conv1-agg + conv2-mm fused: Q = agg128(P,+bg1,relu,*dis)@Wg2
    k_agg_mm5<<<gN64, 256, 0, stream>>>(P, bg1, offs, ssrc, dis, W2f, Q, n);

    // final agg: out = dis*(sum+self)+bg2 -> d_out (fp32)
    k_agg_fin<<<gAgg, 256, 0, stream>>>(Q, bg2, dis, offs, ssrc, (float*)d_out, n);
}

// Round 15
// 354.639 us; speedup vs baseline: 1.1275x; 1.1275x over previous
//
#include <hip/hip_runtime.h>

// Pipeline (R27 = R23 resubmit #3; R25/R26 both failed on bench infra —
// container-acquire and Trio-nursery errors, no kernel signal. This exact
// source benched 356.2us / absmax 0.00390625 in R23):
//   h0 = bf16(dis*relu(relu([x|st]@W1+b1)@W2+b2))   [N,64]  k_mlp (MFMA x2, LDS tile)
//   a0 = bf16(dis[d]*(sum h0[s] + h0[d]))           [N,64]  agg0
//   P  = bf16(dis*(relu(a0@Wg0+bg0)@Wg1))           [N,128] k_cmm (MFMA x2, LDS tile)
//   h2'= bf16(dis[d]*relu(dis[d]*(sum+self)+bg1))   [N,128] agg1 (OSCALE)
//   Q  = bf16(h2'@Wg2)                              [N,64]  mmx5
//   out= dis[d]*(sum+self)+bg2                      [N,64]  agg2 -> d_out (fp32)
//
// R24 lesson: fusing agg into MFMA kernels (wave serially aggs 16 nodes) cut
// the agg grid 16x -> HBM 15% vs 46%, +44us. The random-gather wall is only
// reachable with one-wave-per-node parallelism; NEVER shrink a latency-bound
// gather's grid to co-locate compute.
// R21 lesson: bucketed CSR = write coalescing (random 4B global stores cost
// 16x via line write-allocate). R18 lesson: agg gathers are at the compulsory
// per-XCD traffic wall (~193MB at TCC), structure-independent (5 structures).
// Math: out[d] = dis[d]*(sum_s dis[s]*P[s] + dis[d]*P[d]); with P'[i]=dis[i]*P[i]
// this is dis[d]*(sum_s P'[s] + P'[d]) -- per-edge weights vanish.
// MFMA layouts (guide-verified): A[m=lane&15][k=(lane>>4)*8+j], B mirrored,
// C/D[row=(lane>>4)*4+reg][col=lane&15].

__device__ __forceinline__ unsigned short bf16rne(float f) {
    unsigned u = __float_as_uint(f);
    unsigned r = (u + 0x7fffu + ((u >> 16) & 1u)) >> 16;
    return (unsigned short)r;
}
__device__ __forceinline__ float bf16lo(unsigned v) { return __uint_as_float(v << 16); }
__device__ __forceinline__ float bf16hi(unsigned v) { return __uint_as_float(v & 0xffff0000u); }

using bf16x8 = __attribute__((ext_vector_type(8))) short;
using f32x4  = __attribute__((ext_vector_type(4))) float;

__device__ __forceinline__ bf16x8 pack8(float4 u, float4 v) {
    bf16x8 r;
    r[0] = (short)bf16rne(u.x); r[1] = (short)bf16rne(u.y);
    r[2] = (short)bf16rne(u.z); r[3] = (short)bf16rne(u.w);
    r[4] = (short)bf16rne(v.x); r[5] = (short)bf16rne(v.y);
    r[6] = (short)bf16rne(v.z); r[7] = (short)bf16rne(v.w);
    return r;
}

// ---------------- graph preprocessing: bucketed CSR (dst>>8 buckets) --------
// ep entry: src | ((dst & 255) << 20)   (requires n <= 2^20)

__global__ __launch_bounds__(256) void k_hist(const int* __restrict__ dst, int e, int nb,
                                              int* __restrict__ gh, int* __restrict__ bh) {
    __shared__ int h[512];
    const int t = threadIdx.x;
    h[t] = 0; h[t + 256] = 0;
    __syncthreads();
    const int base = blockIdx.x * 4096;
    const int end = min(base + 4096, e);
    for (int i = base + t; i < end; i += 256) atomicAdd(&h[dst[i] >> 8], 1);
    __syncthreads();
    int* bhrow = bh + (size_t)blockIdx.x * 512;
    for (int b = t; b < nb; b += 256) {
        int c = h[b];
        bhrow[b] = c;
        if (c) atomicAdd(&gh[b], c);
    }
}

__global__ __launch_bounds__(512) void k_scan(const int* __restrict__ gh, int nb, int e, int n,
                                              int* __restrict__ bbase, int* __restrict__ gcur,
                                              int* __restrict__ offs) {
    __shared__ int sm[512];
    const int t = threadIdx.x;
    int v = (t < nb) ? gh[t] : 0;
    sm[t] = v;
    __syncthreads();
    for (int off = 1; off < 512; off <<= 1) {
        int add = (t >= off) ? sm[t - off] : 0;
        __syncthreads();
        sm[t] += add;
        __syncthreads();
    }
    if (t < nb) {
        int excl = sm[t] - v;
        bbase[t] = excl;
        gcur[t] = excl;
    }
    if (t == 0) { bbase[nb] = e; offs[n] = e; }
}

__global__ __launch_bounds__(256) void k_scatter1(const int* __restrict__ src,
                                                  const int* __restrict__ dst, int e, int nb,
                                                  int* __restrict__ gcur,
                                                  const int* __restrict__ bh,
                                                  int* __restrict__ ep) {
    __shared__ int h[512];
    __shared__ int cbase[512];
    const int t = threadIdx.x;
    h[t] = 0; h[t + 256] = 0;
    __syncthreads();
    const int* bhrow = bh + (size_t)blockIdx.x * 512;
    for (int b = t; b < nb; b += 256) {
        int c = bhrow[b];
        cbase[b] = c ? atomicAdd(&gcur[b], c) : 0;
    }
    __syncthreads();
    const int base = blockIdx.x * 4096;
    const int end = min(base + 4096, e);
    for (int i = base + t; i < end; i += 256) {
        int d = dst[i];
        int bn = d >> 8;
        int r = atomicAdd(&h[bn], 1);
        ep[cbase[bn] + r] = src[i] | ((d & 255) << 20);
    }
}

__global__ __launch_bounds__(256) void k_build(const int* __restrict__ ep,
                                               const int* __restrict__ bbase, int n,
                                               int* __restrict__ offs,
                                               int* __restrict__ ssrc,
                                               float* __restrict__ dis) {
    __shared__ int cnt[256];
    __shared__ int sm[256];
    __shared__ int cur[256];
    const int t = threadIdx.x;
    const int b = blockIdx.x;
    const int lo = bbase[b];
    const int hi = bbase[b + 1];
    cnt[t] = 0;
    __syncthreads();
    for (int i = lo + t; i < hi; i += 256) atomicAdd(&cnt[(ep[i] >> 20) & 255], 1);
    __syncthreads();
    int v = cnt[t];
    sm[t] = v;
    __syncthreads();
    for (int off = 1; off < 256; off <<= 1) {
        int add = (t >= off) ? sm[t - off] : 0;
        __syncthreads();
        sm[t] += add;
        __syncthreads();
    }
    const int excl = sm[t] - v;
    const int node = (b << 8) + t;
    if (node < n) {
        offs[node] = lo + excl;
        dis[node] = rsqrtf(1.0f + (float)v);
    }
    cur[t] = lo + excl;
    __syncthreads();
    for (int i = lo + t; i < hi; i += 256) {
        int p = ep[i];
        int pos = atomicAdd(&cur[(p >> 20) & 255], 1);
        ssrc[pos] = p & 0xFFFFF;
    }
}

// ---------------- W -> MFMA fragment-ordered bf16 (fused x5) ----------------
// Wf[((kt*CT+ct)*64+lane)*8 + j] = bf16(W[kt*32+(lane>>4)*8+j][ct*16+(lane&15)])
// Segments: [0,12288) W1 96x128 -> Fa; [12288,20480) W2 128x64 -> Fb;
// [20480,28672) Wg0 64x128 -> F0; [28672,45056) Wg1 128x128 -> F1;
// [45056,53248) Wg2 128x64 -> F2.  Grid: 208 blocks x 256.

__global__ void k_wprep5(const float* __restrict__ W1, const float* __restrict__ W2,
                         const float* __restrict__ G0, const float* __restrict__ G1,
                         const float* __restrict__ G2,
                         unsigned short* __restrict__ Fa, unsigned short* __restrict__ Fb,
                         unsigned short* __restrict__ F0, unsigned short* __restrict__ F1,
                         unsigned short* __restrict__ F2) {
    int t = blockIdx.x * 256 + threadIdx.x;
    const float* W;
    unsigned short* Wf;
    int FOUT;
    if (t < 12288) { W = W1; Wf = Fa; FOUT = 128; }
    else if (t < 20480) { t -= 12288; W = W2; Wf = Fb; FOUT = 64; }
    else if (t < 28672) { t -= 20480; W = G0; Wf = F0; FOUT = 128; }
    else if (t < 45056) { t -= 28672; W = G1; Wf = F1; FOUT = 128; }
    else { t -= 45056; W = G2; Wf = F2; FOUT = 64; }
    const int CT = FOUT / 16;
    int j = t & 7;
    int lane = (t >> 3) & 63;
    int ct = (t >> 9) % CT;
    int kt = t / (512 * CT);
    int k = kt * 32 + (lane >> 4) * 8 + j;
    int c = ct * 16 + (lane & 15);
    Wf[t] = bf16rne(W[(size_t)k * FOUT + c]);
}

// ---------------- MFMA matmul: out[n,FOUT](bf16) = in[n,K](bf16) @ Wf -------

template <int K, int FOUT, bool BIAS, bool RELU, bool SCALE>
__global__ __launch_bounds__(256) void k_mmx(const unsigned short* __restrict__ in,
                                             const unsigned short* __restrict__ Wf,
                                             const float* __restrict__ bias,
                                             const float* __restrict__ dis,
                                             unsigned short* __restrict__ out, int n) {
    constexpr int KT = K / 32;
    constexpr int CT = FOUT / 16;
    const int t = threadIdx.x;
    const int wv = t >> 6;
    const int lane = t & 63;
    const int rowBase = blockIdx.x * 64 + wv * 16;
    const int m = lane & 15;
    const int q = lane >> 4;

    f32x4 acc[CT];
#pragma unroll
    for (int c = 0; c < CT; c++) acc[c] = (f32x4){0.f, 0.f, 0.f, 0.f};

    int arow = rowBase + m;
    if (arow >= n) arow = n - 1;
    const unsigned short* ap = in + (size_t)arow * K + q * 8;
    const bf16x8* wfp = (const bf16x8*)Wf;

#pragma unroll
    for (int kt = 0; kt < KT; kt++) {
        bf16x8 a = *(const bf16x8*)(ap + kt * 32);
#pragma unroll
        for (int c = 0; c < CT; c++) {
            bf16x8 b = wfp[(kt * CT + c) * 64 + lane];
            acc[c] = __builtin_amdgcn_mfma_f32_16x16x32_bf16(a, b, acc[c], 0, 0, 0);
        }
    }

    float bv[CT];
    if constexpr (BIAS) {
#pragma unroll
        for (int c = 0; c < CT; c++) bv[c] = bias[c * 16 + m];
    }

    const int crow = rowBase + q * 4;
#pragma unroll
    for (int r = 0; r < 4; r++) {
        int rr = crow + r;
        if (rr >= n) continue;
        float sc = 1.f;
        if constexpr (SCALE) sc = dis[rr];
#pragma unroll
        for (int c = 0; c < CT; c++) {
            float v = acc[c][r];
            if constexpr (BIAS) v += bv[c];
            if constexpr (RELU) v = fmaxf(v, 0.f);
            if constexpr (SCALE) v *= sc;
            out[(size_t)rr * FOUT + c * 16 + m] = bf16rne(v);
        }
    }
}

// ---------------- fused MLP: h0 = bf16(dis*relu(relu([x|st]@W1+b1)@W2+b2)) --

__global__ __launch_bounds__(256) void k_mlp(const float* __restrict__ x,
                                             const float* __restrict__ st,
                                             const unsigned short* __restrict__ Wa,
                                             const float* __restrict__ b1,
                                             const unsigned short* __restrict__ Wb,
                                             const float* __restrict__ b2,
                                             const float* __restrict__ dis,
                                             unsigned short* __restrict__ h0, int n) {
    constexpr int ROWB = 136;
    __shared__ unsigned short As[64 * ROWB];

    const int t = threadIdx.x;
    const int wv = t >> 6;
    const int lane = t & 63;
    const int rowBase = blockIdx.x * 64 + wv * 16;
    const int m = lane & 15;
    const int q = lane >> 4;

    // ---- phase 1: A = relu([x|st]@W1+b1), K=96, CT=8 ----
    {
        f32x4 acc[8];
#pragma unroll
        for (int c = 0; c < 8; c++) acc[c] = (f32x4){0.f, 0.f, 0.f, 0.f};

        int arow = rowBase + m;
        if (arow >= n) arow = n - 1;
        const float* xp = x + (size_t)arow * 64 + q * 8;
        const float* sp = st + (size_t)arow * 32 + q * 8;

        bf16x8 a0 = pack8(*(const float4*)(xp), *(const float4*)(xp + 4));
        bf16x8 a1 = pack8(*(const float4*)(xp + 32), *(const float4*)(xp + 36));
        bf16x8 a2 = pack8(*(const float4*)(sp), *(const float4*)(sp + 4));

        const bf16x8* wfp = (const bf16x8*)Wa;
#pragma unroll
        for (int c = 0; c < 8; c++) {
            acc[c] = __builtin_amdgcn_mfma_f32_16x16x32_bf16(a0, wfp[c * 64 + lane], acc[c], 0, 0, 0);
            acc[c] = __builtin_amdgcn_mfma_f32_16x16x32_bf16(a1, wfp[(8 + c) * 64 + lane], acc[c], 0, 0, 0);
            acc[c] = __builtin_amdgcn_mfma_f32_16x16x32_bf16(a2, wfp[(16 + c) * 64 + lane], acc[c], 0, 0, 0);
        }

        float bv[8];
#pragma unroll
        for (int c = 0; c < 8; c++) bv[c] = b1[c * 16 + m];

        const int lrow = wv * 16 + q * 4;
#pragma unroll
        for (int r = 0; r < 4; r++) {
#pragma unroll
            for (int c = 0; c < 8; c++) {
                float v = fmaxf(acc[c][r] + bv[c], 0.f);
                As[(lrow + r) * ROWB + c * 16 + m] = bf16rne(v);
            }
        }
    }
    __syncthreads();

    // ---- phase 2: h0 = dis*relu(A@W2+b2), K=128, CT=4 ----
    {
        f32x4 acc[4];
#pragma unroll
        for (int c = 0; c < 4; c++) acc[c] = (f32x4){0.f, 0.f, 0.f, 0.f};

        const unsigned short* ap = As + (wv * 16 + m) * ROWB + q * 8;
        const bf16x8* wfp = (const bf16x8*)Wb;
#pragma unroll
        for (int kt = 0; kt < 4; kt++) {
            bf16x8 a = *(const bf16x8*)(ap + kt * 32);
#pragma unroll
            for (int c = 0; c < 4; c++) {
                acc[c] = __builtin_amdgcn_mfma_f32_16x16x32_bf16(a, wfp[(kt * 4 + c) * 64 + lane], acc[c], 0, 0, 0);
            }
        }

        float bv[4];
#pragma unroll
        for (int c = 0; c < 4; c++) bv[c] = b2[c * 16 + m];

        const int crow = rowBase + q * 4;
#pragma unroll
        for (int r = 0; r < 4; r++) {
            int rr = crow + r;
            if (rr >= n) continue;
            const float sc = dis[rr];
#pragma unroll
            for (int c = 0; c < 4; c++) {
                float v = fmaxf(acc[c][r] + bv[c], 0.f) * sc;
                h0[(size_t)rr * 64 + c * 16 + m] = bf16rne(v);
            }
        }
    }
}

// ---------------- fused conv mm: P = bf16(dis*(relu(a0@Wg0+bg0)@Wg1)) -------

__global__ __launch_bounds__(256) void k_cmm(const unsigned short* __restrict__ a0,
                                             const unsigned short* __restrict__ W0,
                                             const float* __restrict__ bg0,
                                             const unsigned short* __restrict__ W1,
                                             const float* __restrict__ dis,
                                             unsigned short* __restrict__ P, int n) {
    constexpr int ROWB = 136;
    __shared__ unsigned short As[64 * ROWB];

    const int t = threadIdx.x;
    const int wv = t >> 6;
    const int lane = t & 63;
    const int rowBase = blockIdx.x * 64 + wv * 16;
    const int m = lane & 15;
    const int q = lane >> 4;

    // ---- phase 1: h1 = relu(a0@Wg0+bg0), K=64, CT=8 ----
    {
        f32x4 acc[8];
#pragma unroll
        for (int c = 0; c < 8; c++) acc[c] = (f32x4){0.f, 0.f, 0.f, 0.f};

        int arow = rowBase + m;
        if (arow >= n) arow = n - 1;
        const unsigned short* ap = a0 + (size_t)arow * 64 + q * 8;
        const bf16x8* wfp = (const bf16x8*)W0;
#pragma unroll
        for (int kt = 0; kt < 2; kt++) {
            bf16x8 a = *(const bf16x8*)(ap + kt * 32);
#pragma unroll
            for (int c = 0; c < 8; c++) {
                acc[c] = __builtin_amdgcn_mfma_f32_16x16x32_bf16(a, wfp[(kt * 8 + c) * 64 + lane], acc[c], 0, 0, 0);
            }
        }

        float bv[8];
#pragma unroll
        for (int c = 0; c < 8; c++) bv[c] = bg0[c * 16 + m];

        const int lrow = wv * 16 + q * 4;
#pragma unroll
        for (int r = 0; r < 4; r++) {
#pragma unroll
            for (int c = 0; c < 8; c++) {
                float v = fmaxf(acc[c][r] + bv[c], 0.f);
                As[(lrow + r) * ROWB + c * 16 + m] = bf16rne(v);
            }
        }
    }
    __syncthreads();

    // ---- phase 2: P = dis*(h1@Wg1), K=128, CT=8 ----
    {
        f32x4 acc[8];
#pragma unroll
        for (int c = 0; c < 8; c++) acc[c] = (f32x4){0.f, 0.f, 0.f, 0.f};

        const unsigned short* ap = As + (wv * 16 + m) * ROWB + q * 8;
        const bf16x8* wfp = (const bf16x8*)W1;
#pragma unroll
        for (int kt = 0; kt < 4; kt++) {
            bf16x8 a = *(const bf16x8*)(ap + kt * 32);
#pragma unroll
            for (int c = 0; c < 8; c++) {
                acc[c] = __builtin_amdgcn_mfma_f32_16x16x32_bf16(a, wfp[(kt * 8 + c) * 64 + lane], acc[c], 0, 0, 0);
            }
        }

        const int crow = rowBase + q * 4;
#pragma unroll
        for (int r = 0; r < 4; r++) {
            int rr = crow + r;
            if (rr >= n) continue;
            const float sc = dis[rr];
#pragma unroll
            for (int c = 0; c < 8; c++) {
                P[(size_t)rr * 128 + c * 16 + m] = bf16rne(acc[c][r] * sc);
            }
        }
    }
}

// ---------------- GCN aggregation (lane-owns-feature, scalar indices) -------
// Inputs dis-prescaled; inner loop = pure gather-add. One wave per node.
// F=128: lane owns dword `lane`; 16 edges in flight, staircase 16/4/1.
// F=64: half-waves take alternating edges; 32-edge chunks, staircase
// 32/8/2/1; one shfl_xor(32) merge. jb/je readfirstlane'd -> scalar ssrc.
// OB: bf16 out; OSCALE: extra *dis[node] (folds next matmul's prescale).

template <int F, bool RELU, bool OB, bool BIAS, bool OSCALE>
__global__ __launch_bounds__(256) void k_agg(const unsigned short* __restrict__ hW,
                                             const float* __restrict__ bias,
                                             const float* __restrict__ dis,
                                             const int* __restrict__ offs,
                                             const int* __restrict__ ssrc,
                                             void* __restrict__ outv, int n) {
    const int wv = threadIdx.x >> 6;
    const int lane = threadIdx.x & 63;
    const int node = blockIdx.x * 4 + wv;
    if (node >= n) return;
    const int jb = __builtin_amdgcn_readfirstlane(offs[node]);
    const int je = __builtin_amdgcn_readfirstlane(offs[node + 1]);
    const unsigned* hw32 = (const unsigned*)hW;

    float accL = 0.f, accH = 0.f;

#define ADD2(r) do { accL += bf16lo(r); accH += bf16hi(r); } while (0)

    if constexpr (F == 128) {
        const int ld = lane;
        int j = jb;
        for (; j + 16 <= je; j += 16) {
            int s0 = ssrc[j + 0], s1 = ssrc[j + 1], s2 = ssrc[j + 2], s3 = ssrc[j + 3];
            int s4 = ssrc[j + 4], s5 = ssrc[j + 5], s6 = ssrc[j + 6], s7 = ssrc[j + 7];
            int s8 = ssrc[j + 8], s9 = ssrc[j + 9], sa = ssrc[j + 10], sb = ssrc[j + 11];
            int sc = ssrc[j + 12], sd = ssrc[j + 13], se = ssrc[j + 14], sf = ssrc[j + 15];
            unsigned r0 = hw32[(size_t)s0 * 64 + ld];
            unsigned r1 = hw32[(size_t)s1 * 64 + ld];
            unsigned r2 = hw32[(size_t)s2 * 64 + ld];
            unsigned r3 = hw32[(size_t)s3 * 64 + ld];
            unsigned r4 = hw32[(size_t)s4 * 64 + ld];
            unsigned r5 = hw32[(size_t)s5 * 64 + ld];
            unsigned r6 = hw32[(size_t)s6 * 64 + ld];
            unsigned r7 = hw32[(size_t)s7 * 64 + ld];
            unsigned r8 = hw32[(size_t)s8 * 64 + ld];
            unsigned r9 = hw32[(size_t)s9 * 64 + ld];
            unsigned ra = hw32[(size_t)sa * 64 + ld];
            unsigned rb = hw32[(size_t)sb * 64 + ld];
            unsigned rc = hw32[(size_t)sc * 64 + ld];
            unsigned rd = hw32[(size_t)sd * 64 + ld];
            unsigned re = hw32[(size_t)se * 64 + ld];
            unsigned rf = hw32[(size_t)sf * 64 + ld];
            ADD2(r0); ADD2(r1); ADD2(r2); ADD2(r3);
            ADD2(r4); ADD2(r5); ADD2(r6); ADD2(r7);
            ADD2(r8); ADD2(r9); ADD2(ra); ADD2(rb);
            ADD2(rc); ADD2(rd); ADD2(re); ADD2(rf);
        }
        for (; j + 4 <= je; j += 4) {
            int s0 = ssrc[j + 0], s1 = ssrc[j + 1], s2 = ssrc[j + 2], s3 = ssrc[j + 3];
            unsigned r0 = hw32[(size_t)s0 * 64 + ld];
            unsigned r1 = hw32[(size_t)s1 * 64 + ld];
            unsigned r2 = hw32[(size_t)s2 * 64 + ld];
            unsigned r3 = hw32[(size_t)s3 * 64 + ld];
            ADD2(r0); ADD2(r1); ADD2(r2); ADD2(r3);
        }
        for (; j < je; j++) {
            int s = ssrc[j];
            unsigned r = hw32[(size_t)s * 64 + ld];
            ADD2(r);
        }
        unsigned sv = hw32[(size_t)node * 64 + ld];
        const float di = dis[node];
        float v0 = (accL + bf16lo(sv)) * di;
        float v1 = (accH + bf16hi(sv)) * di;
        if constexpr (BIAS) {
            float2 bb = *(const float2*)(bias + ld * 2);
            v0 += bb.x; v1 += bb.y;
        }
        if constexpr (RELU) { v0 = fmaxf(v0, 0.f); v1 = fmaxf(v1, 0.f); }
        if constexpr (OSCALE) { v0 *= di; v1 *= di; }
        if constexpr (OB) {
            ((unsigned*)outv)[(size_t)node * 64 + ld] =
                (unsigned)bf16rne(v0) | ((unsigned)bf16rne(v1) << 16);
        } else {
            *(float2*)((float*)outv + (size_t)node * 128 + ld * 2) = make_float2(v0, v1);
        }
    } else {  // F == 64: 32-dword rows; halves take alternating edges
        const int half = lane >> 5;
        const int hl = lane & 31;
        int j = jb;
        for (; j + 32 <= je; j += 32) {
            int t00 = ssrc[j + 0],  t01 = ssrc[j + 1],  t02 = ssrc[j + 2],  t03 = ssrc[j + 3];
            int t04 = ssrc[j + 4],  t05 = ssrc[j + 5],  t06 = ssrc[j + 6],  t07 = ssrc[j + 7];
            int t08 = ssrc[j + 8],  t09 = ssrc[j + 9],  t10 = ssrc[j + 10], t11 = ssrc[j + 11];
            int t12 = ssrc[j + 12], t13 = ssrc[j + 13], t14 = ssrc[j + 14], t15 = ssrc[j + 15];
            int t16 = ssrc[j + 16], t17 = ssrc[j + 17], t18 = ssrc[j + 18], t19 = ssrc[j + 19];
            int t20 = ssrc[j + 20], t21 = ssrc[j + 21], t22 = ssrc[j + 22], t23 = ssrc[j + 23];
            int t24 = ssrc[j + 24], t25 = ssrc[j + 25], t26 = ssrc[j + 26], t27 = ssrc[j + 27];
            int t28 = ssrc[j + 28], t29 = ssrc[j + 29], t30 = ssrc[j + 30], t31 = ssrc[j + 31];
            int e0 = half ? t01 : t00;
            int e1 = half ? t03 : t02;
            int e2 = half ? t05 : t04;
            int e3 = half ? t07 : t06;
            int e4 = half ? t09 : t08;
            int e5 = half ? t11 : t10;
            int e6 = half ? t13 : t12;
            int e7 = half ? t15 : t14;
            int e8 = half ? t17 : t16;
            int e9 = half ? t19 : t18;
            int ea = half ? t21 : t20;
            int eb = half ? t23 : t22;
            int ec = half ? t25 : t24;
            int ed = half ? t27 : t26;
            int ee = half ? t29 : t28;
            int ef = half ? t31 : t30;
            unsigned r0 = hw32[(size_t)e0 * 32 + hl];
            unsigned r1 = hw32[(size_t)e1 * 32 + hl];
            unsigned r2 = hw32[(size_t)e2 * 32 + hl];
            unsigned r3 = hw32[(size_t)e3 * 32 + hl];
            unsigned r4 = hw32[(size_t)e4 * 32 + hl];
            unsigned r5 = hw32[(size_t)e5 * 32 + hl];
            unsigned r6 = hw32[(size_t)e6 * 32 + hl];
            unsigned r7 = hw32[(size_t)e7 * 32 + hl];
            unsigned r8 = hw32[(size_t)e8 * 32 + hl];
            unsigned r9 = hw32[(size_t)e9 * 32 + hl];
            unsigned ra = hw32[(size_t)ea * 32 + hl];
            unsigned rb = hw32[(size_t)eb * 32 + hl];
            unsigned rc = hw32[(size_t)ec * 32 + hl];
            unsigned rd = hw32[(size_t)ed * 32 + hl];
            unsigned re = hw32[(size_t)ee * 32 + hl];
            unsigned rf = hw32[(size_t)ef * 32 + hl];
            ADD2(r0); ADD2(r1); ADD2(r2); ADD2(r3);
            ADD2(r4); ADD2(r5); ADD2(r6); ADD2(r7);
            ADD2(r8); ADD2(r9); ADD2(ra); ADD2(rb);
            ADD2(rc); ADD2(rd); ADD2(re); ADD2(rf);
        }
        for (; j + 8 <= je; j += 8) {
            int t0 = ssrc[j + 0], t1 = ssrc[j + 1], t2 = ssrc[j + 2], t3 = ssrc[j + 3];
            int t4 = ssrc[j + 4], t5 = ssrc[j + 5], t6 = ssrc[j + 6], t7 = ssrc[j + 7];
            int e0 = half ? t1 : t0;
            int e1 = half ? t3 : t2;
            int e2 = half ? t5 : t4;
            int e3 = half ? t7 : t6;
            unsigned r0 = hw32[(size_t)e0 * 32 + hl];
            unsigned r1 = hw32[(size_t)e1 * 32 + hl];
            unsigned r2 = hw32[(size_t)e2 * 32 + hl];
            unsigned r3 = hw32[(size_t)e3 * 32 + hl];
            ADD2(r0); ADD2(r1); ADD2(r2); ADD2(r3);
        }
        for (; j + 2 <= je; j += 2) {
            int t0 = ssrc[j], t1 = ssrc[j + 1];
            int e0 = half ? t1 : t0;
            unsigned r = hw32[(size_t)e0 * 32 + hl];
            ADD2(r);
        }
        if (j < je) {
            int s = ssrc[j];
            unsigned r = hw32[(size_t)s * 32 + hl];
            if (half == 0) { ADD2(r); }
        }
        accL += __shfl_xor(accL, 32);
        accH += __shfl_xor(accH, 32);
        if (half == 0) {
            unsigned sv = hw32[(size_t)node * 32 + hl];
            const float di = dis[node];
            float v0 = (accL + bf16lo(sv)) * di;
            float v1 = (accH + bf16hi(sv)) * di;
            if constexpr (BIAS) {
                float2 bb = *(const float2*)(bias + hl * 2);
                v0 += bb.x; v1 += bb.y;
            }
            if constexpr (RELU) { v0 = fmaxf(v0, 0.f); v1 = fmaxf(v1, 0.f); }
            if constexpr (OSCALE) { v0 *= di; v1 *= di; }
            if constexpr (OB) {
                ((unsigned*)outv)[(size_t)node * 32 + hl] =
                    (unsigned)bf16rne(v0) | ((unsigned)bf16rne(v1) << 16);
            } else {
                *(float2*)((float*)outv + (size_t)node * 64 + hl * 2) = make_float2(v0, v1);
            }
        }
    }
#undef ADD2
}

// ---------------- launch -----------------------------------------------------

extern "C" void kernel_launch(void* const* d_in, const int* in_sizes, int n_in,
                              void* d_out, int out_size, void* d_ws, size_t ws_size,
                              hipStream_t stream) {
    const float* x   = (const float*)d_in[0];
    const float* st  = (const float*)d_in[1];
    const int*   src = (const int*)d_in[2];
    const int*   dst = (const int*)d_in[3];
    const float* W1  = (const float*)d_in[4];
    const float* b1  = (const float*)d_in[5];
    const float* W2  = (const float*)d_in[6];
    const float* b2  = (const float*)d_in[7];
    const float* Wg0 = (const float*)d_in[8];
    const float* bg0 = (const float*)d_in[9];
    const float* Wg1 = (const float*)d_in[10];
    const float* bg1 = (const float*)d_in[11];
    const float* Wg2 = (const float*)d_in[12];
    const float* bg2 = (const float*)d_in[13];

    const int n = in_sizes[0] / 64;  // IN_DIM = 64
    const int e = in_sizes[2];
    const int nb = (n + 255) >> 8;
    const int gE4k = (e + 4095) / 4096;

    char* wp = (char*)d_ws;
    auto carve = [&](size_t bytes) {
        void* p = (void*)wp;
        wp += (bytes + 255) & ~(size_t)255;
        return p;
    };
    int*   ghist = (int*)carve(512 * 4);
    int*   gcur  = (int*)carve(512 * 4);
    int*   bbase = (int*)carve(513 * 4);
    int*   bh    = (int*)carve((size_t)gE4k * 512 * 4);
    int*   offs  = (int*)carve((size_t)(n + 1) * 4);
    float* dis   = (float*)carve((size_t)n * 4);
    int*   ssrc  = (int*)carve((size_t)e * 4);
    char*  R3    = (char*)carve((size_t)n * 128 * 4);  // ep -> a0|h2
    char*  R2    = (char*)carve((size_t)n * 64 * 2);   // h0 -> Q
    unsigned short* Waf = (unsigned short*)carve((size_t)96 * 128 * 2);
    unsigned short* Wbf = (unsigned short*)carve((size_t)128 * 64 * 2);
    unsigned short* W0f = (unsigned short*)carve((size_t)64 * 128 * 2);
    unsigned short* W1f = (unsigned short*)carve((size_t)128 * 128 * 2);
    unsigned short* W2f = (unsigned short*)carve((size_t)128 * 64 * 2);

    // aliases (stream-ordered lifetimes):
    int* ep = (int*)R3;                                   // dead after k_build
    unsigned short* a0 = (unsigned short*)R3;             // agg0 out (n*64 bf16)
    unsigned short* h2 = (unsigned short*)(R3 + (size_t)n * 128 * 2);  // agg1 out
    unsigned short* h0 = (unsigned short*)R2;             // k_mlp out (dis-scaled)
    unsigned short* Q  = (unsigned short*)R2;             // mmx5 out
    unsigned short* P  = (unsigned short*)d_out;          // k_cmm out (n*128 bf16)

    hipMemsetAsync(ghist, 0, 512 * 4, stream);

    const int gN64 = (n + 63) / 64;
    const int gAgg = (n + 3) / 4;

    // graph prep (bucketed CSR: write-coalesced scatter)
    k_hist<<<gE4k, 256, 0, stream>>>(dst, e, nb, ghist, bh);
    k_scan<<<1, 512, 0, stream>>>(ghist, nb, e, n, bbase, gcur, offs);
    k_scatter1<<<gE4k, 256, 0, stream>>>(src, dst, e, nb, gcur, bh, ep);
    k_build<<<nb, 256, 0, stream>>>(ep, bbase, n, offs, ssrc, dis);

    // W fragment prep (fused x5): 53248 elements = 208 blocks
    k_wprep5<<<208, 256, 0, stream>>>(W1, W2, Wg0, Wg1, Wg2, Waf, Wbf, W0f, W1f, W2f);

    // fused MLP (mmx1+mmx2): h0 = dis*relu(relu([x|st]@W1+b1)@W2+b2)
    k_mlp<<<gN64, 256, 0, stream>>>(x, st, Waf, b1, Wbf, b2, dis, h0, n);

    // conv0 agg at F=64 (agg(h)@W == agg(h@W)); then fused mmx3+mmx4:
    k_agg<64, false, true, false, false><<<gAgg, 256, 0, stream>>>(h0, nullptr, dis, offs, ssrc, a0, n);
    k_cmm<<<gN64, 256, 0, stream>>>(a0, W0f, bg0, W1f, dis, P, n);

    // conv1 agg@128 (dis+bias+relu, then *dis folded from mmx5's prescale)
    k_agg<128, true, true, true, true><<<gAgg, 256, 0, stream>>>(P, bg1, dis, offs, ssrc, h2, n);

    // conv2: MFMA mm (input already dis-scaled) -> agg@64 (dis+bias, fp32) -> d_out
    k_mmx<128, 64, false, false, false><<<gN64, 256, 0, stream>>>(h2, W2f, nullptr, nullptr, Q, n);
    k_agg<64, false, false, true, false><<<gAgg, 256, 0, stream>>>(Q, bg2, dis, offs, ssrc,
                                                                   (float*)d_out, n);
}